// Round 1
// baseline (67.884 us; speedup 1.0000x reference)
//
#include <hip/hip_runtime.h>

#define H 128
#define W 128
#define Zd 16
#define C 20
#define HWZ (H * W * Zd)   // 262144 spatial positions
#define CHWZ (C * HWZ)     // 5242880 elements

// MODE 0: X-step, spatial plane (h,w), gates guidance[0..7],  neighbor (h+di, w+dj)
// MODE 1: Y-step, spatial plane (h,z), gates guidance[8..15], neighbor (h+di, z+dj)
// MODE 2: Z-step, spatial plane (w,z), gates guidance[16..23],neighbor (w+di, z+dj)
template <int MODE>
__global__ __launch_bounds__(256) void prop_kernel(const float* __restrict__ gd,
                                                   const float* __restrict__ in,
                                                   float* __restrict__ out) {
    int tid = blockIdx.x * blockDim.x + threadIdx.x;
    int z = tid & (Zd - 1);
    int w = (tid >> 4) & (W - 1);
    int h = tid >> 11;

    // k -> (di,dj), di = 1-top, dj = 1-left per PADS table
    const int DI[8] = {1, 1, 1, 0, 0, -1, -1, -1};
    const int DJ[8] = {1, 0, -1, 1, -1, 1, 0, -1};

    float g[8];
    int noff[8];
    float A = 0.f, S = 0.f;

#pragma unroll
    for (int k = 0; k < 8; ++k) {
        const int di = DI[k], dj = DJ[k];
        bool valid;
        float val = 0.f;
        int delta;
        if (MODE == 0) {
            int hh = h + di, ww = w + dj;
            valid = ((unsigned)hh < H) && ((unsigned)ww < W);
            if (valid) val = gd[((k * H + hh) * W + ww) * Zd + z];
            delta = (di * W + dj) * Zd;
        } else if (MODE == 1) {
            int hh = h + di, zz = z + dj;
            valid = ((unsigned)hh < H) && ((unsigned)zz < Zd);
            if (valid) val = gd[(((8 + k) * H + hh) * W + w) * Zd + zz];
            delta = di * W * Zd + dj;
        } else {
            int ww = w + di, zz = z + dj;
            valid = ((unsigned)ww < W) && ((unsigned)zz < Zd);
            if (valid) val = gd[(((16 + k) * H + h) * W + ww) * Zd + zz];
            delta = di * Zd + dj;
        }
        g[k] = val;                 // 0 when invalid
        noff[k] = valid ? delta : 0; // safe address when invalid (g[k]==0 kills it)
        A += fabsf(val);
        S += val;
    }

    const float invA = 1.0f / A;
    const float c0 = 1.0f - S * invA;
#pragma unroll
    for (int k = 0; k < 8; ++k) g[k] *= invA;

    const int base = (h * W + w) * Zd + z;
#pragma unroll 4
    for (int c = 0; c < C; ++c) {
        const float* __restrict__ inc = in + c * HWZ;
        float acc = c0 * inc[base];
#pragma unroll
        for (int k = 0; k < 8; ++k) {
            acc += g[k] * inc[base + noff[k]];
        }
        out[c * HWZ + base] = acc;
    }
}

extern "C" void kernel_launch(void* const* d_in, const int* in_sizes, int n_in,
                              void* d_out, int out_size, void* d_ws, size_t ws_size,
                              hipStream_t stream) {
    const float* gd = (const float*)d_in[0];   // guidance (24,128,128,16) f32
    const float* blur = (const float*)d_in[1]; // blur (20,128,128,16) f32
    float* out = (float*)d_out;                // (20,128,128,16) f32
    float* ws = (float*)d_ws;                  // need >= 21 MB

    dim3 block(256);
    dim3 grid(HWZ / 256);
    prop_kernel<0><<<grid, block, 0, stream>>>(gd, blur, out); // X: blur -> out
    prop_kernel<1><<<grid, block, 0, stream>>>(gd, out, ws);   // Y: out  -> ws
    prop_kernel<2><<<grid, block, 0, stream>>>(gd, ws, out);   // Z: ws   -> out
}

// Round 2
// 57.394 us; speedup vs baseline: 1.1828x; 1.1828x over previous
//
#include <hip/hip_runtime.h>

#define H 128
#define W 128
#define Zd 16
#define C 20
#define HWZ (H * W * Zd)   // 262144 spatial positions

typedef float f4 __attribute__((ext_vector_type(4)));

__device__ __forceinline__ f4 load4(const float* p) { return *(const f4*)p; }
// unaligned (4B-aligned) 16B load
__device__ __forceinline__ f4 load4u(const float* p) {
    f4 r;
    __builtin_memcpy(&r, p, 16);
    return r;
}

// ---------------- X step: taps shift in (h,w), z untouched -> all loads aligned
__global__ __launch_bounds__(256) void prop_x(const float* __restrict__ gd,
                                              const float* __restrict__ in,
                                              float* __restrict__ out) {
    int tid = blockIdx.x * blockDim.x + threadIdx.x; // 65536 threads
    int z4 = (tid & 3) << 2;
    int w = (tid >> 2) & (W - 1);
    int h = tid >> 9;

    const int DI[8] = {1, 1, 1, 0, 0, -1, -1, -1};
    const int DJ[8] = {1, 0, -1, 1, -1, 1, 0, -1};

    f4 g[8];
    int noff[8];
    f4 A = {0, 0, 0, 0}, S = {0, 0, 0, 0};
#pragma unroll
    for (int k = 0; k < 8; ++k) {
        int hh = h + DI[k], ww = w + DJ[k];
        bool valid = ((unsigned)hh < H) && ((unsigned)ww < W);
        f4 val = {0, 0, 0, 0};
        if (valid) val = load4(gd + ((k * H + hh) * W + ww) * Zd + z4);
        g[k] = val;
        noff[k] = valid ? (DI[k] * W + DJ[k]) * Zd : 0;
#pragma unroll
        for (int e = 0; e < 4; ++e) A[e] += __builtin_fabsf(val[e]);
        S += val;
    }
    f4 invA = 1.0f / A;
    f4 c0 = 1.0f - S * invA;
#pragma unroll
    for (int k = 0; k < 8; ++k) g[k] *= invA;

    const int base = (h * W + w) * Zd + z4;
#pragma unroll 2
    for (int c = 0; c < C; ++c) {
        const float* pc = in + c * HWZ + base;
        f4 acc = c0 * load4(pc);
#pragma unroll
        for (int k = 0; k < 8; ++k) acc += g[k] * load4(pc + noff[k]);
        *(f4*)(out + c * HWZ + base) = acc;
    }
}

// ---------------- Y/Z steps: taps shift in (row, z). MODE=1: row=h, MODE=2: row=w.
template <int MODE>
__global__ __launch_bounds__(256) void prop_z(const float* __restrict__ gd,
                                              const float* __restrict__ in,
                                              float* __restrict__ out) {
    constexpr int GOFF = 8 * MODE;                  // gate block: 8 or 16
    constexpr int RS = (MODE == 1) ? W * Zd : Zd;   // row stride in elements
    constexpr int RMAX = (MODE == 1) ? H : W;

    int tid = blockIdx.x * blockDim.x + threadIdx.x;
    int z4 = (tid & 3) << 2;
    int w = (tid >> 2) & (W - 1);
    int h = tid >> 9;
    int rc = (MODE == 1) ? h : w;

    const int DI[8] = {1, 1, 1, 0, 0, -1, -1, -1};
    const int DJ[8] = {1, 0, -1, 1, -1, 1, 0, -1};

    const int gbase = ((GOFF * H + h) * W + w) * Zd + z4;

    f4 g[8];
    f4 A = {0, 0, 0, 0}, S = {0, 0, 0, 0};
#pragma unroll
    for (int k = 0; k < 8; ++k) {
        int di = DI[k], dj = DJ[k];
        bool rv = (unsigned)(rc + di) < RMAX;
        f4 val = {0, 0, 0, 0};
        if (rv) {
            // z-shifted gate load; 4B-aligned only when dj != 0
            val = (dj == 0) ? load4(gd + gbase + k * HWZ + di * RS)
                            : load4u(gd + gbase + k * HWZ + di * RS + dj);
            if (dj == -1 && z4 == 0) val[0] = 0.f;   // zz = -1 invalid
            if (dj == 1 && z4 == 12) val[3] = 0.f;   // zz = 16 invalid
        }
        g[k] = val;
#pragma unroll
        for (int e = 0; e < 4; ++e) A[e] += __builtin_fabsf(val[e]);
        S += val;
    }
    f4 invA = 1.0f / A;
    f4 c0 = 1.0f - S * invA;
#pragma unroll
    for (int k = 0; k < 8; ++k) g[k] *= invA;

    // group gates by row: r=0 -> di=+1, r=1 -> di=0, r=2 -> di=-1
    f4 gp[3] = {g[0], g[3], g[5]};  // dj = +1
    f4 gc[3] = {g[1], c0, g[6]};    // dj =  0 (center row uses c0)
    f4 gm[3] = {g[2], g[4], g[7]};  // dj = -1

    const int base = (h * W + w) * Zd + z4;
    const int DIr[3] = {1, 0, -1};
    int rowoff[3];
#pragma unroll
    for (int r = 0; r < 3; ++r)
        rowoff[r] = ((unsigned)(rc + DIr[r]) < RMAX) ? DIr[r] * RS : 0;

    const int loo = (z4 == 0) ? 0 : -1;   // clamped edge-scalar offsets (gate=0 when clamped)
    const int hio = (z4 == 12) ? 3 : 4;

#pragma unroll 2
    for (int c = 0; c < C; ++c) {
        const float* pc = in + c * HWZ + base;
        f4 acc = {0, 0, 0, 0};
#pragma unroll
        for (int r = 0; r < 3; ++r) {
            const float* pr = pc + rowoff[r];
            f4 v = load4(pr);
            float lo = pr[loo];
            float hi = pr[hio];
            f4 tm = {lo, v[0], v[1], v[2]};
            f4 tp = {v[1], v[2], v[3], hi};
            acc += gm[r] * tm + gc[r] * v + gp[r] * tp;
        }
        *(f4*)(out + c * HWZ + base) = acc;
    }
}

extern "C" void kernel_launch(void* const* d_in, const int* in_sizes, int n_in,
                              void* d_out, int out_size, void* d_ws, size_t ws_size,
                              hipStream_t stream) {
    const float* gd = (const float*)d_in[0];   // guidance (24,128,128,16) f32
    const float* blur = (const float*)d_in[1]; // blur (20,128,128,16) f32
    float* out = (float*)d_out;                // (20,128,128,16) f32
    float* ws = (float*)d_ws;

    dim3 block(256);
    dim3 grid((HWZ / 4) / 256);  // 256 blocks, one thread per 4 z
    prop_x<<<grid, block, 0, stream>>>(gd, blur, out);      // X: blur -> out
    prop_z<1><<<grid, block, 0, stream>>>(gd, out, ws);     // Y: out  -> ws
    prop_z<2><<<grid, block, 0, stream>>>(gd, ws, out);     // Z: ws   -> out
}

// Round 3
// 55.619 us; speedup vs baseline: 1.2205x; 1.0319x over previous
//
#include <hip/hip_runtime.h>

#define H 128
#define W 128
#define Zd 16
#define C 20
#define HWZ (H * W * Zd)   // 262144 spatial positions

#define CG 5               // channel groups
#define CPG (C / CG)       // 4 channels per thread
#define POSBLOCKS 256      // blocks covering the 65536 position-threads

typedef float f4 __attribute__((ext_vector_type(4)));

__device__ __forceinline__ f4 load4(const float* p) { return *(const f4*)p; }
// unaligned (4B-aligned) 16B load
__device__ __forceinline__ f4 load4u(const float* p) {
    f4 r;
    __builtin_memcpy(&r, p, 16);
    return r;
}

// ---------------- X step: taps shift in (h,w), z untouched -> all loads aligned
__global__ __launch_bounds__(256) void prop_x(const float* __restrict__ gd,
                                              const float* __restrict__ in,
                                              float* __restrict__ out) {
    const int cg = blockIdx.x / POSBLOCKS;
    const int tid = (blockIdx.x % POSBLOCKS) * blockDim.x + threadIdx.x;
    const int z4 = (tid & 3) << 2;
    const int w = (tid >> 2) & (W - 1);
    const int h = tid >> 9;

    const int DI[8] = {1, 1, 1, 0, 0, -1, -1, -1};
    const int DJ[8] = {1, 0, -1, 1, -1, 1, 0, -1};

    f4 g[8];
    int noff[8];
    f4 A = {0, 0, 0, 0}, S = {0, 0, 0, 0};
#pragma unroll
    for (int k = 0; k < 8; ++k) {
        int hh = h + DI[k], ww = w + DJ[k];
        bool valid = ((unsigned)hh < H) && ((unsigned)ww < W);
        f4 val = {0, 0, 0, 0};
        if (valid) val = load4(gd + ((k * H + hh) * W + ww) * Zd + z4);
        g[k] = val;
        noff[k] = valid ? (DI[k] * W + DJ[k]) * Zd : 0;
#pragma unroll
        for (int e = 0; e < 4; ++e) A[e] += __builtin_fabsf(val[e]);
        S += val;
    }
    f4 invA = 1.0f / A;
    f4 c0 = 1.0f - S * invA;
#pragma unroll
    for (int k = 0; k < 8; ++k) g[k] *= invA;

    const int base = (h * W + w) * Zd + z4;
#pragma unroll
    for (int cc = 0; cc < CPG; ++cc) {
        const int c = cg * CPG + cc;
        const float* pc = in + c * HWZ + base;
        f4 acc = c0 * load4(pc);
#pragma unroll
        for (int k = 0; k < 8; ++k) acc += g[k] * load4(pc + noff[k]);
        *(f4*)(out + c * HWZ + base) = acc;
    }
}

// ---------------- Y/Z steps: taps shift in (row, z). MODE=1: row=h, MODE=2: row=w.
template <int MODE>
__global__ __launch_bounds__(256) void prop_z(const float* __restrict__ gd,
                                              const float* __restrict__ in,
                                              float* __restrict__ out) {
    constexpr int GOFF = 8 * MODE;                  // gate block: 8 or 16
    constexpr int RS = (MODE == 1) ? W * Zd : Zd;   // row stride in elements
    constexpr int RMAX = (MODE == 1) ? H : W;

    const int cg = blockIdx.x / POSBLOCKS;
    const int tid = (blockIdx.x % POSBLOCKS) * blockDim.x + threadIdx.x;
    const int z4 = (tid & 3) << 2;
    const int w = (tid >> 2) & (W - 1);
    const int h = tid >> 9;
    const int rc = (MODE == 1) ? h : w;

    const int DI[8] = {1, 1, 1, 0, 0, -1, -1, -1};
    const int DJ[8] = {1, 0, -1, 1, -1, 1, 0, -1};

    const int gbase = ((GOFF * H + h) * W + w) * Zd + z4;

    f4 g[8];
    f4 A = {0, 0, 0, 0}, S = {0, 0, 0, 0};
#pragma unroll
    for (int k = 0; k < 8; ++k) {
        int di = DI[k], dj = DJ[k];
        bool rv = (unsigned)(rc + di) < RMAX;
        f4 val = {0, 0, 0, 0};
        if (rv) {
            val = (dj == 0) ? load4(gd + gbase + k * HWZ + di * RS)
                            : load4u(gd + gbase + k * HWZ + di * RS + dj);
            if (dj == -1 && z4 == 0) val[0] = 0.f;   // zz = -1 invalid
            if (dj == 1 && z4 == 12) val[3] = 0.f;   // zz = 16 invalid
        }
        g[k] = val;
#pragma unroll
        for (int e = 0; e < 4; ++e) A[e] += __builtin_fabsf(val[e]);
        S += val;
    }
    f4 invA = 1.0f / A;
    f4 c0 = 1.0f - S * invA;
#pragma unroll
    for (int k = 0; k < 8; ++k) g[k] *= invA;

    // group gates by row: r=0 -> di=+1, r=1 -> di=0, r=2 -> di=-1
    f4 gp[3] = {g[0], g[3], g[5]};  // dj = +1
    f4 gc[3] = {g[1], c0, g[6]};    // dj =  0 (center row uses c0)
    f4 gm[3] = {g[2], g[4], g[7]};  // dj = -1

    const int base = (h * W + w) * Zd + z4;
    const int DIr[3] = {1, 0, -1};
    int rowoff[3];
#pragma unroll
    for (int r = 0; r < 3; ++r)
        rowoff[r] = ((unsigned)(rc + DIr[r]) < RMAX) ? DIr[r] * RS : 0;

    const int loo = (z4 == 0) ? 0 : -1;   // clamped edge-scalar offsets (gate=0 when clamped)
    const int hio = (z4 == 12) ? 3 : 4;

#pragma unroll
    for (int cc = 0; cc < CPG; ++cc) {
        const int c = cg * CPG + cc;
        const float* pc = in + c * HWZ + base;
        f4 acc = {0, 0, 0, 0};
#pragma unroll
        for (int r = 0; r < 3; ++r) {
            const float* pr = pc + rowoff[r];
            f4 v = load4(pr);
            float lo = pr[loo];
            float hi = pr[hio];
            f4 tm = {lo, v[0], v[1], v[2]};
            f4 tp = {v[1], v[2], v[3], hi};
            acc += gm[r] * tm + gc[r] * v + gp[r] * tp;
        }
        *(f4*)(out + c * HWZ + base) = acc;
    }
}

extern "C" void kernel_launch(void* const* d_in, const int* in_sizes, int n_in,
                              void* d_out, int out_size, void* d_ws, size_t ws_size,
                              hipStream_t stream) {
    const float* gd = (const float*)d_in[0];   // guidance (24,128,128,16) f32
    const float* blur = (const float*)d_in[1]; // blur (20,128,128,16) f32
    float* out = (float*)d_out;                // (20,128,128,16) f32
    float* ws = (float*)d_ws;

    dim3 block(256);
    dim3 grid(POSBLOCKS * CG);  // 1280 blocks: 5 channel-groups x 256 position-blocks
    prop_x<<<grid, block, 0, stream>>>(gd, blur, out);      // X: blur -> out
    prop_z<1><<<grid, block, 0, stream>>>(gd, out, ws);     // Y: out  -> ws
    prop_z<2><<<grid, block, 0, stream>>>(gd, ws, out);     // Z: ws   -> out
}

// Round 4
// 43.736 us; speedup vs baseline: 1.5521x; 1.2717x over previous
//
#include <hip/hip_runtime.h>

#define H 128
#define W 128
#define Zd 16
#define C 20
#define HWZ (H * W * Zd)   // 262144 spatial positions

#define CG 5               // channel groups
#define CPG (C / CG)       // 4 channels per thread
#define POSBLOCKS 256      // blocks covering the 65536 position-threads
#define NXCD 8

typedef float f4 __attribute__((ext_vector_type(4)));

__device__ __forceinline__ f4 load4(const float* p) { return *(const f4*)p; }
// unaligned (4B-aligned) 16B load
__device__ __forceinline__ f4 load4u(const float* p) {
    f4 r;
    __builtin_memcpy(&r, p, 16);
    return r;
}

// XCD-aware decode: hardware assigns consecutive blockIdx round-robin to the 8
// XCDs (xcd = bid & 7). Give XCD x the h-slab [16x,16x+16) for ALL 5 channel
// groups -> per-XCD read set (gates slab + input slab) ~4MB, fits its L2;
// gate maps fetched from L3 once per XCD instead of 5x.
__device__ __forceinline__ void decode(int bid, int tidx, int& cg, int& tid) {
    int xcd = bid & (NXCD - 1);
    int i = bid >> 3;          // 0..159
    cg = i >> 5;               // 0..4
    int pb = (xcd << 5) + (i & 31);  // posblock 0..255, contiguous h per XCD
    tid = pb * 256 + tidx;
}

// ---------------- X step: taps shift in (h,w), z untouched -> all loads aligned
__global__ __launch_bounds__(256) void prop_x(const float* __restrict__ gd,
                                              const float* __restrict__ in,
                                              float* __restrict__ out) {
    int cg, tid;
    decode(blockIdx.x, threadIdx.x, cg, tid);
    const int z4 = (tid & 3) << 2;
    const int w = (tid >> 2) & (W - 1);
    const int h = tid >> 9;

    const int DI[8] = {1, 1, 1, 0, 0, -1, -1, -1};
    const int DJ[8] = {1, 0, -1, 1, -1, 1, 0, -1};

    f4 g[8];
    int noff[8];
    f4 A = {0, 0, 0, 0}, S = {0, 0, 0, 0};
#pragma unroll
    for (int k = 0; k < 8; ++k) {
        int hh = h + DI[k], ww = w + DJ[k];
        bool valid = ((unsigned)hh < H) && ((unsigned)ww < W);
        f4 val = {0, 0, 0, 0};
        if (valid) val = load4(gd + ((k * H + hh) * W + ww) * Zd + z4);
        g[k] = val;
        noff[k] = valid ? (DI[k] * W + DJ[k]) * Zd : 0;
#pragma unroll
        for (int e = 0; e < 4; ++e) A[e] += __builtin_fabsf(val[e]);
        S += val;
    }
    f4 invA = 1.0f / A;
    f4 c0 = 1.0f - S * invA;
#pragma unroll
    for (int k = 0; k < 8; ++k) g[k] *= invA;

    const int base = (h * W + w) * Zd + z4;
#pragma unroll
    for (int cc = 0; cc < CPG; ++cc) {
        const int c = cg * CPG + cc;
        const float* pc = in + c * HWZ + base;
        f4 acc = c0 * load4(pc);
#pragma unroll
        for (int k = 0; k < 8; ++k) acc += g[k] * load4(pc + noff[k]);
        *(f4*)(out + c * HWZ + base) = acc;
    }
}

// ---------------- Y/Z steps: taps shift in (row, z). MODE=1: row=h, MODE=2: row=w.
template <int MODE>
__global__ __launch_bounds__(256) void prop_z(const float* __restrict__ gd,
                                              const float* __restrict__ in,
                                              float* __restrict__ out) {
    constexpr int GOFF = 8 * MODE;                  // gate block: 8 or 16
    constexpr int RS = (MODE == 1) ? W * Zd : Zd;   // row stride in elements
    constexpr int RMAX = (MODE == 1) ? H : W;

    int cg, tid;
    decode(blockIdx.x, threadIdx.x, cg, tid);
    const int z4 = (tid & 3) << 2;
    const int w = (tid >> 2) & (W - 1);
    const int h = tid >> 9;
    const int rc = (MODE == 1) ? h : w;

    const int DI[8] = {1, 1, 1, 0, 0, -1, -1, -1};
    const int DJ[8] = {1, 0, -1, 1, -1, 1, 0, -1};

    const int gbase = ((GOFF * H + h) * W + w) * Zd + z4;

    f4 g[8];
    f4 A = {0, 0, 0, 0}, S = {0, 0, 0, 0};
#pragma unroll
    for (int k = 0; k < 8; ++k) {
        int di = DI[k], dj = DJ[k];
        bool rv = (unsigned)(rc + di) < RMAX;
        f4 val = {0, 0, 0, 0};
        if (rv) {
            val = (dj == 0) ? load4(gd + gbase + k * HWZ + di * RS)
                            : load4u(gd + gbase + k * HWZ + di * RS + dj);
            if (dj == -1 && z4 == 0) val[0] = 0.f;   // zz = -1 invalid
            if (dj == 1 && z4 == 12) val[3] = 0.f;   // zz = 16 invalid
        }
        g[k] = val;
#pragma unroll
        for (int e = 0; e < 4; ++e) A[e] += __builtin_fabsf(val[e]);
        S += val;
    }
    f4 invA = 1.0f / A;
    f4 c0 = 1.0f - S * invA;
#pragma unroll
    for (int k = 0; k < 8; ++k) g[k] *= invA;

    // group gates by row: r=0 -> di=+1, r=1 -> di=0, r=2 -> di=-1
    f4 gp[3] = {g[0], g[3], g[5]};  // dj = +1
    f4 gc[3] = {g[1], c0, g[6]};    // dj =  0 (center row uses c0)
    f4 gm[3] = {g[2], g[4], g[7]};  // dj = -1

    const int base = (h * W + w) * Zd + z4;
    const int DIr[3] = {1, 0, -1};
    int rowoff[3];
#pragma unroll
    for (int r = 0; r < 3; ++r)
        rowoff[r] = ((unsigned)(rc + DIr[r]) < RMAX) ? DIr[r] * RS : 0;

    const int loo = (z4 == 0) ? 0 : -1;   // clamped edge-scalar offsets (gate=0 when clamped)
    const int hio = (z4 == 12) ? 3 : 4;

#pragma unroll
    for (int cc = 0; cc < CPG; ++cc) {
        const int c = cg * CPG + cc;
        const float* pc = in + c * HWZ + base;
        f4 acc = {0, 0, 0, 0};
#pragma unroll
        for (int r = 0; r < 3; ++r) {
            const float* pr = pc + rowoff[r];
            f4 v = load4(pr);
            float lo = pr[loo];
            float hi = pr[hio];
            f4 tm = {lo, v[0], v[1], v[2]};
            f4 tp = {v[1], v[2], v[3], hi};
            acc += gm[r] * tm + gc[r] * v + gp[r] * tp;
        }
        *(f4*)(out + c * HWZ + base) = acc;
    }
}

extern "C" void kernel_launch(void* const* d_in, const int* in_sizes, int n_in,
                              void* d_out, int out_size, void* d_ws, size_t ws_size,
                              hipStream_t stream) {
    const float* gd = (const float*)d_in[0];   // guidance (24,128,128,16) f32
    const float* blur = (const float*)d_in[1]; // blur (20,128,128,16) f32
    float* out = (float*)d_out;                // (20,128,128,16) f32
    float* ws = (float*)d_ws;

    dim3 block(256);
    dim3 grid(POSBLOCKS * CG);  // 1280 blocks: 8 XCD-slabs x 5 cgroups x 32 posblocks
    prop_x<<<grid, block, 0, stream>>>(gd, blur, out);      // X: blur -> out
    prop_z<1><<<grid, block, 0, stream>>>(gd, out, ws);     // Y: out  -> ws
    prop_z<2><<<grid, block, 0, stream>>>(gd, ws, out);     // Z: ws   -> out
}

// Round 5
// 33.701 us; speedup vs baseline: 2.0143x; 1.2978x over previous
//
#include <hip/hip_runtime.h>

#define H 128
#define W 128
#define Zd 16
#define C 20
#define HWZ (H * W * Zd)   // 262144 spatial positions

#define CG 5               // channel groups for prop_x
#define CPG (C / CG)       // 4 channels per thread
#define POSBLOCKS 256
#define NXCD 8

#define CGF 4              // channel groups for fused yz
#define CPGF (C / CGF)     // 5 channels per block

typedef float f4 __attribute__((ext_vector_type(4)));

__device__ __forceinline__ f4 load4(const float* p) { return *(const f4*)p; }
__device__ __forceinline__ f4 load4u(const float* p) {
    f4 r;
    __builtin_memcpy(&r, p, 16);
    return r;
}

// XCD-aware decode for prop_x: XCD x owns h-slab [16x,16x+16) for all 5 cgroups.
__device__ __forceinline__ void decode(int bid, int tidx, int& cg, int& tid) {
    int xcd = bid & (NXCD - 1);
    int i = bid >> 3;          // 0..159
    cg = i >> 5;               // 0..4
    int pb = (xcd << 5) + (i & 31);
    tid = pb * 256 + tidx;
}

// ---------------- X step: taps shift in (h,w), z untouched
__global__ __launch_bounds__(256) void prop_x(const float* __restrict__ gd,
                                              const float* __restrict__ in,
                                              float* __restrict__ out) {
    int cg, tid;
    decode(blockIdx.x, threadIdx.x, cg, tid);
    const int z4 = (tid & 3) << 2;
    const int w = (tid >> 2) & (W - 1);
    const int h = tid >> 9;

    const int DI[8] = {1, 1, 1, 0, 0, -1, -1, -1};
    const int DJ[8] = {1, 0, -1, 1, -1, 1, 0, -1};

    f4 g[8];
    int noff[8];
    f4 A = {0, 0, 0, 0}, S = {0, 0, 0, 0};
#pragma unroll
    for (int k = 0; k < 8; ++k) {
        int hh = h + DI[k], ww = w + DJ[k];
        bool valid = ((unsigned)hh < H) && ((unsigned)ww < W);
        f4 val = {0, 0, 0, 0};
        if (valid) val = load4(gd + ((k * H + hh) * W + ww) * Zd + z4);
        g[k] = val;
        noff[k] = valid ? (DI[k] * W + DJ[k]) * Zd : 0;
#pragma unroll
        for (int e = 0; e < 4; ++e) A[e] += __builtin_fabsf(val[e]);
        S += val;
    }
    f4 invA = 1.0f / A;
    f4 c0 = 1.0f - S * invA;
#pragma unroll
    for (int k = 0; k < 8; ++k) g[k] *= invA;

    const int base = (h * W + w) * Zd + z4;
#pragma unroll
    for (int cc = 0; cc < CPG; ++cc) {
        const int c = cg * CPG + cc;
        const float* pc = in + c * HWZ + base;
        f4 acc = c0 * load4(pc);
#pragma unroll
        for (int k = 0; k < 8; ++k) acc += g[k] * load4(pc + noff[k]);
        *(f4*)(out + c * HWZ + base) = acc;
    }
}

// ---------------- Fused Y+Z: one block owns one h-row (full W x Z) x 5 channels.
// Y step (taps h+-1, z+-1) reads global X-out, stores Y-out row to LDS;
// Z step (taps w+-1, z+-1 -- NO h dependency) reads LDS, writes final out.
__global__ __launch_bounds__(512) void prop_yz(const float* __restrict__ gd,
                                               const float* __restrict__ in,
                                               float* __restrict__ out) {
    // grid = 512 blocks: xcd(8) x cgf(4) x rowin(16); XCD x owns rows [16x,16x+16)
    const int bid = blockIdx.x;
    const int xcd = bid & (NXCD - 1);
    const int i = bid >> 3;     // 0..63
    const int cgf = i >> 4;     // 0..3
    const int h = (xcd << 4) + (i & 15);

    const int t = threadIdx.x;  // 0..511
    const int z4 = (t & 3) << 2;
    const int w = t >> 2;       // 0..127

    __shared__ float yout[CPGF][W][Zd];   // 40 KB

    const int DI[8] = {1, 1, 1, 0, 0, -1, -1, -1};
    const int DJ[8] = {1, 0, -1, 1, -1, 1, 0, -1};
    const int base = (h * W + w) * Zd + z4;
    const int loo = (z4 == 0) ? 0 : -1;
    const int hio = (z4 == 12) ? 3 : 4;

    // ======== Y step (gates 8..15, row = h, row stride W*Zd) ========
    {
        const int gbase = (((8 * H) + h) * W + w) * Zd + z4;
        f4 g[8];
        f4 A = {0, 0, 0, 0}, S = {0, 0, 0, 0};
#pragma unroll
        for (int k = 0; k < 8; ++k) {
            int di = DI[k], dj = DJ[k];
            bool rv = (unsigned)(h + di) < H;
            f4 val = {0, 0, 0, 0};
            if (rv) {
                val = (dj == 0) ? load4(gd + gbase + k * HWZ + di * (W * Zd))
                                : load4u(gd + gbase + k * HWZ + di * (W * Zd) + dj);
                if (dj == -1 && z4 == 0) val[0] = 0.f;
                if (dj == 1 && z4 == 12) val[3] = 0.f;
            }
            g[k] = val;
#pragma unroll
            for (int e = 0; e < 4; ++e) A[e] += __builtin_fabsf(val[e]);
            S += val;
        }
        f4 invA = 1.0f / A;
        f4 c0 = 1.0f - S * invA;
#pragma unroll
        for (int k = 0; k < 8; ++k) g[k] *= invA;

        f4 gp[3] = {g[0], g[3], g[5]};
        f4 gc[3] = {g[1], c0, g[6]};
        f4 gm[3] = {g[2], g[4], g[7]};
        const int DIr[3] = {1, 0, -1};
        int rowoff[3];
#pragma unroll
        for (int r = 0; r < 3; ++r)
            rowoff[r] = ((unsigned)(h + DIr[r]) < H) ? DIr[r] * (W * Zd) : 0;

#pragma unroll
        for (int cc = 0; cc < CPGF; ++cc) {
            const int c = cgf * CPGF + cc;
            const float* pc = in + c * HWZ + base;
            f4 acc = {0, 0, 0, 0};
#pragma unroll
            for (int r = 0; r < 3; ++r) {
                const float* pr = pc + rowoff[r];
                f4 v = load4(pr);
                float lo = pr[loo];
                float hi = pr[hio];
                f4 tm = {lo, v[0], v[1], v[2]};
                f4 tp = {v[1], v[2], v[3], hi};
                acc += gm[r] * tm + gc[r] * v + gp[r] * tp;
            }
            *(f4*)(&yout[cc][w][z4]) = acc;
        }
    }

    __syncthreads();

    // ======== Z step (gates 16..23, row = w, row stride Zd) ========
    {
        const int gbase = (((16 * H) + h) * W + w) * Zd + z4;
        f4 g[8];
        f4 A = {0, 0, 0, 0}, S = {0, 0, 0, 0};
#pragma unroll
        for (int k = 0; k < 8; ++k) {
            int di = DI[k], dj = DJ[k];
            bool rv = (unsigned)(w + di) < W;
            f4 val = {0, 0, 0, 0};
            if (rv) {
                val = (dj == 0) ? load4(gd + gbase + k * HWZ + di * Zd)
                                : load4u(gd + gbase + k * HWZ + di * Zd + dj);
                if (dj == -1 && z4 == 0) val[0] = 0.f;
                if (dj == 1 && z4 == 12) val[3] = 0.f;
            }
            g[k] = val;
#pragma unroll
            for (int e = 0; e < 4; ++e) A[e] += __builtin_fabsf(val[e]);
            S += val;
        }
        f4 invA = 1.0f / A;
        f4 c0 = 1.0f - S * invA;
#pragma unroll
        for (int k = 0; k < 8; ++k) g[k] *= invA;

        f4 gp[3] = {g[0], g[3], g[5]};
        f4 gc[3] = {g[1], c0, g[6]};
        f4 gm[3] = {g[2], g[4], g[7]};
        const int DIr[3] = {1, 0, -1};
        int woff[3];  // LDS float offset for row w+di
#pragma unroll
        for (int r = 0; r < 3; ++r)
            woff[r] = ((unsigned)(w + DIr[r]) < W) ? DIr[r] * Zd : 0;

#pragma unroll
        for (int cc = 0; cc < CPGF; ++cc) {
            const int c = cgf * CPGF + cc;
            const float* pl = &yout[cc][w][z4];
            f4 acc = {0, 0, 0, 0};
#pragma unroll
            for (int r = 0; r < 3; ++r) {
                const float* pr = pl + woff[r];
                f4 v = load4(pr);
                float lo = pr[loo];
                float hi = pr[hio];
                f4 tm = {lo, v[0], v[1], v[2]};
                f4 tp = {v[1], v[2], v[3], hi};
                acc += gm[r] * tm + gc[r] * v + gp[r] * tp;
            }
            *(f4*)(out + c * HWZ + base) = acc;
        }
    }
}

extern "C" void kernel_launch(void* const* d_in, const int* in_sizes, int n_in,
                              void* d_out, int out_size, void* d_ws, size_t ws_size,
                              hipStream_t stream) {
    const float* gd = (const float*)d_in[0];   // guidance (24,128,128,16) f32
    const float* blur = (const float*)d_in[1]; // blur (20,128,128,16) f32
    float* out = (float*)d_out;                // (20,128,128,16) f32
    float* ws = (float*)d_ws;

    prop_x<<<dim3(POSBLOCKS * CG), dim3(256), 0, stream>>>(gd, blur, ws); // X: blur -> ws
    prop_yz<<<dim3(512), dim3(512), 0, stream>>>(gd, ws, out);            // Y+Z: ws -> out
}